// Round 1
// baseline (462.993 us; speedup 1.0000x reference)
//
#include <hip/hip_runtime.h>

// Problem constants (from reference setup_inputs)
#define B_   2
#define C_   256
#define H_   200
#define W_   304
#define N_   512
#define OH_  7
#define OW_  7
#define POS_ 49          // OH_*OW_
#define CPB_ 12544       // C_*POS_  (outputs per box)

__global__ __launch_bounds__(256) void rroi_align_kernel(
    const float* __restrict__ fm,     // (B, C, H, W)
    const float* __restrict__ boxes,  // (B, N, 5)
    float* __restrict__ out)          // (B*N, C, 7, 7)
{
    __shared__ int4   sOff[POS_];   // 4 clipped linear offsets within a channel plane
    __shared__ float4 sWgt[POS_];   // 4 bilinear weights with validity folded in

    const int bn  = blockIdx.x;       // 0 .. B*N-1
    const int b   = bn >> 9;          // N_ = 512
    const int tid = threadIdx.x;

    if (tid < POS_) {
        const float* bx = boxes + (size_t)bn * 5;
        const float cx = bx[0], cy = bx[1], w = bx[2], h = bx[3], ang = bx[4];

        const float rad = -ang * 0.017453292519943295f;   // -pi/180
        const float cr = cosf(rad), sr = sinf(rad);

        const float a00 =  w * (1.0f / W_) * cr;
        const float a01 = -h * (1.0f / H_) * sr;
        const float a02 =  2.0f * cx * (1.0f / W_) - 1.0f;
        const float a10 =  w * (1.0f / W_) * sr;
        const float a11 =  h * (1.0f / H_) * cr;
        const float a12 =  2.0f * cy * (1.0f / H_) - 1.0f;

        const int py = tid / OW_;
        const int px = tid - py * OW_;
        const float xs = (2.0f * (float)px + 1.0f) / (float)OW_ - 1.0f;
        const float ys = (2.0f * (float)py + 1.0f) / (float)OH_ - 1.0f;

        const float gx = a00 * xs + a01 * ys + a02;
        const float gy = a10 * xs + a11 * ys + a12;

        const float ix = ((gx + 1.0f) * (float)W_ - 1.0f) * 0.5f;
        const float iy = ((gy + 1.0f) * (float)H_ - 1.0f) * 0.5f;

        const float x0f = floorf(ix), y0f = floorf(iy);
        const float wx1 = ix - x0f,  wy1 = iy - y0f;
        const float wx0 = 1.0f - wx1, wy0 = 1.0f - wy1;
        const float x1f = x0f + 1.0f, y1f = y0f + 1.0f;

        const float vx0 = (x0f >= 0.0f && x0f <= (float)(W_ - 1)) ? 1.0f : 0.0f;
        const float vx1 = (x1f >= 0.0f && x1f <= (float)(W_ - 1)) ? 1.0f : 0.0f;
        const float vy0 = (y0f >= 0.0f && y0f <= (float)(H_ - 1)) ? 1.0f : 0.0f;
        const float vy1 = (y1f >= 0.0f && y1f <= (float)(H_ - 1)) ? 1.0f : 0.0f;

        const int xi0 = (int)fminf(fmaxf(x0f, 0.0f), (float)(W_ - 1));
        const int xi1 = (int)fminf(fmaxf(x1f, 0.0f), (float)(W_ - 1));
        const int yi0 = (int)fminf(fmaxf(y0f, 0.0f), (float)(H_ - 1));
        const int yi1 = (int)fminf(fmaxf(y1f, 0.0f), (float)(H_ - 1));

        sOff[tid] = make_int4(yi0 * W_ + xi0, yi0 * W_ + xi1,
                              yi1 * W_ + xi0, yi1 * W_ + xi1);
        sWgt[tid] = make_float4(wy0 * wx0 * (vy0 * vx0),
                                wy0 * wx1 * (vy0 * vx1),
                                wy1 * wx0 * (vy1 * vx0),
                                wy1 * wx1 * (vy1 * vx1));
    }
    __syncthreads();

    const float* __restrict__ fb = fm + (size_t)b * C_ * H_ * W_;
    float* __restrict__ ob = out + (size_t)bn * CPB_;

    #pragma unroll 7
    for (int it = 0; it < POS_; ++it) {
        const int flat = it * 256 + tid;        // 0 .. 12543
        const int c    = flat / POS_;           // magic-number div
        const int pos  = flat - c * POS_;

        const int4   o  = sOff[pos];
        const float4 wv = sWgt[pos];
        const float* __restrict__ plane = fb + c * (H_ * W_);

        const float v = wv.x * plane[o.x] + wv.y * plane[o.y]
                      + wv.z * plane[o.z] + wv.w * plane[o.w];
        ob[flat] = v;                            // fully coalesced
    }
}

extern "C" void kernel_launch(void* const* d_in, const int* in_sizes, int n_in,
                              void* d_out, int out_size, void* d_ws, size_t ws_size,
                              hipStream_t stream) {
    const float* fm    = (const float*)d_in[0];
    const float* boxes = (const float*)d_in[1];
    float* out         = (float*)d_out;

    dim3 grid(B_ * N_);   // one block per box
    dim3 block(256);
    rroi_align_kernel<<<grid, block, 0, stream>>>(fm, boxes, out);
}

// Round 2
// 247.784 us; speedup vs baseline: 1.8685x; 1.8685x over previous
//
#include <hip/hip_runtime.h>

// Problem constants (from reference setup_inputs)
#define B_   2
#define C_   256
#define H_   200
#define W_   304
#define HW_  60800       // H_*W_
#define N_   512
#define OH_  7
#define OW_  7
#define POS_ 49          // OH_*OW_
#define CPB_ 12544       // C_*POS_  (outputs per box)
#define PD_  257         // LDS out-staging pitch (pos-major), odd -> bank-friendly

// ---------------------------------------------------------------------------
// Pass 1: transpose (B, C, HW) -> (B, HW, C) so channel is innermost.
// 64x64 tiles via LDS, float4 global on both sides, +1 padding in LDS.
// ---------------------------------------------------------------------------
__global__ __launch_bounds__(256) void transpose_kernel(
    const float* __restrict__ fm,   // (B, C, HW)
    float* __restrict__ fmT)        // (B, HW, C)
{
    __shared__ float tile[64 * 65];

    const int blk = blockIdx.x;          // 0 .. 2*950*4 - 1
    const int b   = blk / 3800;          // 950*4
    const int r   = blk - b * 3800;
    const int hwT = r >> 2;              // 0..949
    const int cT  = r & 3;               // 0..3
    const int hw0 = hwT * 64;
    const int c0  = cT * 64;

    const int t      = threadIdx.x;
    const int lane16 = t & 15;           // 0..15
    const int grp    = t >> 4;           // 0..15

    const float* src = fm + ((size_t)b * C_ + c0) * HW_ + hw0;

    #pragma unroll
    for (int p = 0; p < 4; ++p) {
        const int c_local = p * 16 + grp;
        const float4 v = *(const float4*)(src + (size_t)c_local * HW_ + lane16 * 4);
        float* dl = &tile[c_local * 65 + lane16 * 4];
        dl[0] = v.x; dl[1] = v.y; dl[2] = v.z; dl[3] = v.w;
    }
    __syncthreads();

    float* dst = fmT + ((size_t)b * HW_ + hw0) * C_ + c0;

    #pragma unroll
    for (int p = 0; p < 4; ++p) {
        const int hw_local = p * 16 + grp;
        float4 v;
        v.x = tile[(lane16 * 4 + 0) * 65 + hw_local];
        v.y = tile[(lane16 * 4 + 1) * 65 + hw_local];
        v.z = tile[(lane16 * 4 + 2) * 65 + hw_local];
        v.w = tile[(lane16 * 4 + 3) * 65 + hw_local];
        *(float4*)(dst + (size_t)hw_local * C_ + lane16 * 4) = v;
    }
}

// ---------------------------------------------------------------------------
// Pass 2: gather. One block per box; lane = channel. Every tap load is a
// fully-coalesced 256-float segment. Output staged through LDS so global
// stores remain flat-coalesced in the (c*49+pos) output layout.
// ---------------------------------------------------------------------------
__global__ __launch_bounds__(256) void gather_kernel(
    const float* __restrict__ fmT,    // (B, HW, C)
    const float* __restrict__ boxes,  // (B, N, 5)
    float* __restrict__ out)          // (B*N, C, 7, 7)
{
    __shared__ int4   sOff[POS_];         // 4 tap base offsets (already *C_)
    __shared__ float4 sWgt[POS_];         // 4 weights with validity folded in
    __shared__ float  sVal[48 * PD_ + 256]; // [pos*PD_ + c]

    const int bn  = blockIdx.x;       // 0 .. B*N-1
    const int b   = bn >> 9;          // N_ = 512
    const int tid = threadIdx.x;      // = channel

    if (tid < POS_) {
        const float* bx = boxes + (size_t)bn * 5;
        const float cx = bx[0], cy = bx[1], w = bx[2], h = bx[3], ang = bx[4];

        const float rad = -ang * 0.017453292519943295f;   // -pi/180
        const float cr = cosf(rad), sr = sinf(rad);

        const float a00 =  w * (1.0f / W_) * cr;
        const float a01 = -h * (1.0f / H_) * sr;
        const float a02 =  2.0f * cx * (1.0f / W_) - 1.0f;
        const float a10 =  w * (1.0f / W_) * sr;
        const float a11 =  h * (1.0f / H_) * cr;
        const float a12 =  2.0f * cy * (1.0f / H_) - 1.0f;

        const int py = tid / OW_;
        const int px = tid - py * OW_;
        const float xs = (2.0f * (float)px + 1.0f) / (float)OW_ - 1.0f;
        const float ys = (2.0f * (float)py + 1.0f) / (float)OH_ - 1.0f;

        const float gx = a00 * xs + a01 * ys + a02;
        const float gy = a10 * xs + a11 * ys + a12;

        const float ix = ((gx + 1.0f) * (float)W_ - 1.0f) * 0.5f;
        const float iy = ((gy + 1.0f) * (float)H_ - 1.0f) * 0.5f;

        const float x0f = floorf(ix), y0f = floorf(iy);
        const float wx1 = ix - x0f,  wy1 = iy - y0f;
        const float wx0 = 1.0f - wx1, wy0 = 1.0f - wy1;
        const float x1f = x0f + 1.0f, y1f = y0f + 1.0f;

        const float vx0 = (x0f >= 0.0f && x0f <= (float)(W_ - 1)) ? 1.0f : 0.0f;
        const float vx1 = (x1f >= 0.0f && x1f <= (float)(W_ - 1)) ? 1.0f : 0.0f;
        const float vy0 = (y0f >= 0.0f && y0f <= (float)(H_ - 1)) ? 1.0f : 0.0f;
        const float vy1 = (y1f >= 0.0f && y1f <= (float)(H_ - 1)) ? 1.0f : 0.0f;

        const int xi0 = (int)fminf(fmaxf(x0f, 0.0f), (float)(W_ - 1));
        const int xi1 = (int)fminf(fmaxf(x1f, 0.0f), (float)(W_ - 1));
        const int yi0 = (int)fminf(fmaxf(y0f, 0.0f), (float)(H_ - 1));
        const int yi1 = (int)fminf(fmaxf(y1f, 0.0f), (float)(H_ - 1));

        sOff[tid] = make_int4((yi0 * W_ + xi0) * C_, (yi0 * W_ + xi1) * C_,
                              (yi1 * W_ + xi0) * C_, (yi1 * W_ + xi1) * C_);
        sWgt[tid] = make_float4(wy0 * wx0 * (vy0 * vx0),
                                wy0 * wx1 * (vy0 * vx1),
                                wy1 * wx0 * (vy1 * vx0),
                                wy1 * wx1 * (vy1 * vx1));
    }
    __syncthreads();

    const float* __restrict__ fb = fmT + (size_t)b * HW_ * C_ + tid;

    #pragma unroll 7
    for (int pos = 0; pos < POS_; ++pos) {
        const int4   o  = sOff[pos];
        const float4 wv = sWgt[pos];
        const float v = wv.x * fb[o.x] + wv.y * fb[o.y]
                      + wv.z * fb[o.z] + wv.w * fb[o.w];
        sVal[pos * PD_ + tid] = v;
    }
    __syncthreads();

    float* __restrict__ ob = out + (size_t)bn * CPB_;

    #pragma unroll 7
    for (int it = 0; it < POS_; ++it) {
        const int flat = it * 256 + tid;
        const int c    = flat / POS_;
        const int pos  = flat - c * POS_;
        ob[flat] = sVal[pos * PD_ + c];   // coalesced global store
    }
}

// ---------------------------------------------------------------------------
// Fallback (R0 kernel): direct gather from (B,C,H,W) — used only if the
// workspace is too small for the transposed feature map.
// ---------------------------------------------------------------------------
__global__ __launch_bounds__(256) void rroi_align_fallback(
    const float* __restrict__ fm,
    const float* __restrict__ boxes,
    float* __restrict__ out)
{
    __shared__ int4   sOff[POS_];
    __shared__ float4 sWgt[POS_];

    const int bn  = blockIdx.x;
    const int b   = bn >> 9;
    const int tid = threadIdx.x;

    if (tid < POS_) {
        const float* bx = boxes + (size_t)bn * 5;
        const float cx = bx[0], cy = bx[1], w = bx[2], h = bx[3], ang = bx[4];
        const float rad = -ang * 0.017453292519943295f;
        const float cr = cosf(rad), sr = sinf(rad);
        const float a00 =  w * (1.0f / W_) * cr;
        const float a01 = -h * (1.0f / H_) * sr;
        const float a02 =  2.0f * cx * (1.0f / W_) - 1.0f;
        const float a10 =  w * (1.0f / W_) * sr;
        const float a11 =  h * (1.0f / H_) * cr;
        const float a12 =  2.0f * cy * (1.0f / H_) - 1.0f;
        const int py = tid / OW_;
        const int px = tid - py * OW_;
        const float xs = (2.0f * (float)px + 1.0f) / (float)OW_ - 1.0f;
        const float ys = (2.0f * (float)py + 1.0f) / (float)OH_ - 1.0f;
        const float gx = a00 * xs + a01 * ys + a02;
        const float gy = a10 * xs + a11 * ys + a12;
        const float ix = ((gx + 1.0f) * (float)W_ - 1.0f) * 0.5f;
        const float iy = ((gy + 1.0f) * (float)H_ - 1.0f) * 0.5f;
        const float x0f = floorf(ix), y0f = floorf(iy);
        const float wx1 = ix - x0f,  wy1 = iy - y0f;
        const float wx0 = 1.0f - wx1, wy0 = 1.0f - wy1;
        const float x1f = x0f + 1.0f, y1f = y0f + 1.0f;
        const float vx0 = (x0f >= 0.0f && x0f <= (float)(W_ - 1)) ? 1.0f : 0.0f;
        const float vx1 = (x1f >= 0.0f && x1f <= (float)(W_ - 1)) ? 1.0f : 0.0f;
        const float vy0 = (y0f >= 0.0f && y0f <= (float)(H_ - 1)) ? 1.0f : 0.0f;
        const float vy1 = (y1f >= 0.0f && y1f <= (float)(H_ - 1)) ? 1.0f : 0.0f;
        const int xi0 = (int)fminf(fmaxf(x0f, 0.0f), (float)(W_ - 1));
        const int xi1 = (int)fminf(fmaxf(x1f, 0.0f), (float)(W_ - 1));
        const int yi0 = (int)fminf(fmaxf(y0f, 0.0f), (float)(H_ - 1));
        const int yi1 = (int)fminf(fmaxf(y1f, 0.0f), (float)(H_ - 1));
        sOff[tid] = make_int4(yi0 * W_ + xi0, yi0 * W_ + xi1,
                              yi1 * W_ + xi0, yi1 * W_ + xi1);
        sWgt[tid] = make_float4(wy0 * wx0 * (vy0 * vx0),
                                wy0 * wx1 * (vy0 * vx1),
                                wy1 * wx0 * (vy1 * vx0),
                                wy1 * wx1 * (vy1 * vx1));
    }
    __syncthreads();

    const float* __restrict__ fb = fm + (size_t)b * C_ * HW_;
    float* __restrict__ ob = out + (size_t)bn * CPB_;

    #pragma unroll 7
    for (int it = 0; it < POS_; ++it) {
        const int flat = it * 256 + tid;
        const int c    = flat / POS_;
        const int pos  = flat - c * POS_;
        const int4   o  = sOff[pos];
        const float4 wv = sWgt[pos];
        const float* __restrict__ plane = fb + (size_t)c * HW_;
        ob[flat] = wv.x * plane[o.x] + wv.y * plane[o.y]
                 + wv.z * plane[o.z] + wv.w * plane[o.w];
    }
}

extern "C" void kernel_launch(void* const* d_in, const int* in_sizes, int n_in,
                              void* d_out, int out_size, void* d_ws, size_t ws_size,
                              hipStream_t stream) {
    const float* fm    = (const float*)d_in[0];
    const float* boxes = (const float*)d_in[1];
    float* out         = (float*)d_out;

    const size_t needed = (size_t)B_ * C_ * HW_ * sizeof(float);  // 124.5 MB

    if (ws_size >= needed) {
        float* fmT = (float*)d_ws;
        transpose_kernel<<<dim3(2 * 950 * 4), dim3(256), 0, stream>>>(fm, fmT);
        gather_kernel<<<dim3(B_ * N_), dim3(256), 0, stream>>>(fmT, boxes, out);
    } else {
        rroi_align_fallback<<<dim3(B_ * N_), dim3(256), 0, stream>>>(fm, boxes, out);
    }
}

// Round 3
// 226.399 us; speedup vs baseline: 2.0450x; 1.0945x over previous
//
#include <hip/hip_runtime.h>
#include <hip/hip_fp16.h>

// Problem constants (from reference setup_inputs)
#define B_   2
#define C_   256
#define H_   200
#define W_   304
#define HW_  60800       // H_*W_
#define N_   512
#define OH_  7
#define OW_  7
#define POS_ 49          // OH_*OW_
#define CPB_ 12544       // C_*POS_  (outputs per box)
#define PD_  258         // LDS out-staging pitch (even -> float2-aligned)

// ---------------------------------------------------------------------------
// Pass 1: transpose + fp32->fp16 convert: (B, C, HW) -> (B, HW, C) half.
// 64x64 tiles via fp32 LDS (known-good R1 structure), half4 (8B) stores.
// ---------------------------------------------------------------------------
__global__ __launch_bounds__(256) void transpose_f16_kernel(
    const float* __restrict__ fm,   // (B, C, HW) fp32
    __half* __restrict__ fmT)       // (B, HW, C) fp16
{
    __shared__ float tile[64 * 65];

    const int blk = blockIdx.x;          // 0 .. 2*950*4 - 1
    const int b   = blk / 3800;          // 950*4
    const int r   = blk - b * 3800;
    const int hwT = r >> 2;              // 0..949
    const int cT  = r & 3;               // 0..3
    const int hw0 = hwT * 64;
    const int c0  = cT * 64;

    const int t      = threadIdx.x;
    const int lane16 = t & 15;           // 0..15
    const int grp    = t >> 4;           // 0..15

    const float* src = fm + ((size_t)b * C_ + c0) * HW_ + hw0;

    #pragma unroll
    for (int p = 0; p < 4; ++p) {
        const int c_local = p * 16 + grp;
        const float4 v = *(const float4*)(src + (size_t)c_local * HW_ + lane16 * 4);
        float* dl = &tile[c_local * 65 + lane16 * 4];
        dl[0] = v.x; dl[1] = v.y; dl[2] = v.z; dl[3] = v.w;
    }
    __syncthreads();

    __half* dst = fmT + ((size_t)b * HW_ + hw0) * C_ + c0;

    #pragma unroll
    for (int p = 0; p < 4; ++p) {
        const int hw_local = p * 16 + grp;
        ushort4 u;
        u.x = __half_as_ushort(__float2half_rn(tile[(lane16 * 4 + 0) * 65 + hw_local]));
        u.y = __half_as_ushort(__float2half_rn(tile[(lane16 * 4 + 1) * 65 + hw_local]));
        u.z = __half_as_ushort(__float2half_rn(tile[(lane16 * 4 + 2) * 65 + hw_local]));
        u.w = __half_as_ushort(__float2half_rn(tile[(lane16 * 4 + 3) * 65 + hw_local]));
        // 8B store: dst byte offset = hw_local*512 + lane16*8 -> 8B aligned
        *(ushort4*)(dst + (size_t)hw_local * C_ + lane16 * 4) = u;
    }
}

// ---------------------------------------------------------------------------
// Pass 2: gather from fp16 channel-inner layout. One block per box.
// Thread handles 2 channels via __half2; tid>>7 splits even/odd positions.
// Output staged through LDS so global stores stay flat-coalesced.
// ---------------------------------------------------------------------------
__global__ __launch_bounds__(256) void gather_f16_kernel(
    const __half* __restrict__ fmT,   // (B, HW, C) fp16
    const float* __restrict__ boxes,  // (B, N, 5)
    float* __restrict__ out)          // (B*N, C, 7, 7) fp32
{
    __shared__ int4   sOff[POS_];          // 4 tap offsets (pre-scaled by C_)
    __shared__ float4 sWgt[POS_];          // 4 weights with validity folded in
    __shared__ float  sVal[48 * PD_ + 256]; // [pos*PD_ + c]

    const int bn  = blockIdx.x;       // 0 .. B*N-1
    const int b   = bn >> 9;          // N_ = 512
    const int tid = threadIdx.x;

    if (tid < POS_) {
        const float* bx = boxes + (size_t)bn * 5;
        const float cx = bx[0], cy = bx[1], w = bx[2], h = bx[3], ang = bx[4];

        const float rad = -ang * 0.017453292519943295f;   // -pi/180
        const float cr = cosf(rad), sr = sinf(rad);

        const float a00 =  w * (1.0f / W_) * cr;
        const float a01 = -h * (1.0f / H_) * sr;
        const float a02 =  2.0f * cx * (1.0f / W_) - 1.0f;
        const float a10 =  w * (1.0f / W_) * sr;
        const float a11 =  h * (1.0f / H_) * cr;
        const float a12 =  2.0f * cy * (1.0f / H_) - 1.0f;

        const int py = tid / OW_;
        const int px = tid - py * OW_;
        const float xs = (2.0f * (float)px + 1.0f) / (float)OW_ - 1.0f;
        const float ys = (2.0f * (float)py + 1.0f) / (float)OH_ - 1.0f;

        const float gx = a00 * xs + a01 * ys + a02;
        const float gy = a10 * xs + a11 * ys + a12;

        const float ix = ((gx + 1.0f) * (float)W_ - 1.0f) * 0.5f;
        const float iy = ((gy + 1.0f) * (float)H_ - 1.0f) * 0.5f;

        const float x0f = floorf(ix), y0f = floorf(iy);
        const float wx1 = ix - x0f,  wy1 = iy - y0f;
        const float wx0 = 1.0f - wx1, wy0 = 1.0f - wy1;
        const float x1f = x0f + 1.0f, y1f = y0f + 1.0f;

        const float vx0 = (x0f >= 0.0f && x0f <= (float)(W_ - 1)) ? 1.0f : 0.0f;
        const float vx1 = (x1f >= 0.0f && x1f <= (float)(W_ - 1)) ? 1.0f : 0.0f;
        const float vy0 = (y0f >= 0.0f && y0f <= (float)(H_ - 1)) ? 1.0f : 0.0f;
        const float vy1 = (y1f >= 0.0f && y1f <= (float)(H_ - 1)) ? 1.0f : 0.0f;

        const int xi0 = (int)fminf(fmaxf(x0f, 0.0f), (float)(W_ - 1));
        const int xi1 = (int)fminf(fmaxf(x1f, 0.0f), (float)(W_ - 1));
        const int yi0 = (int)fminf(fmaxf(y0f, 0.0f), (float)(H_ - 1));
        const int yi1 = (int)fminf(fmaxf(y1f, 0.0f), (float)(H_ - 1));

        sOff[tid] = make_int4((yi0 * W_ + xi0) * C_, (yi0 * W_ + xi1) * C_,
                              (yi1 * W_ + xi0) * C_, (yi1 * W_ + xi1) * C_);
        sWgt[tid] = make_float4(wy0 * wx0 * (vy0 * vx0),
                                wy0 * wx1 * (vy0 * vx1),
                                wy1 * wx0 * (vy1 * vx0),
                                wy1 * wx1 * (vy1 * vx1));
    }
    __syncthreads();

    const int t128 = tid & 127;
    const int pg   = tid >> 7;          // 0: even pos, 1: odd pos
    const int c    = t128 * 2;

    const __half* __restrict__ fb = fmT + (size_t)b * HW_ * C_ + c;

    for (int pos = pg; pos < POS_; pos += 2) {
        const int4   o  = sOff[pos];
        const float4 wv = sWgt[pos];

        const float2 f0 = __half22float2(*(const __half2*)(fb + o.x));
        const float2 f1 = __half22float2(*(const __half2*)(fb + o.y));
        const float2 f2 = __half22float2(*(const __half2*)(fb + o.z));
        const float2 f3 = __half22float2(*(const __half2*)(fb + o.w));

        const float vx = wv.x * f0.x + wv.y * f1.x + wv.z * f2.x + wv.w * f3.x;
        const float vy = wv.x * f0.y + wv.y * f1.y + wv.z * f2.y + wv.w * f3.y;

        *(float2*)&sVal[pos * PD_ + c] = make_float2(vx, vy);
    }
    __syncthreads();

    float* __restrict__ ob = out + (size_t)bn * CPB_;

    #pragma unroll 7
    for (int it = 0; it < POS_; ++it) {
        const int flat = it * 256 + tid;
        const int cc   = flat / POS_;
        const int pos  = flat - cc * POS_;
        ob[flat] = sVal[pos * PD_ + cc];   // coalesced global store
    }
}

// ---------------------------------------------------------------------------
// Fallback (R0 kernel): direct gather from (B,C,H,W) fp32 — used only if the
// workspace is too small for the fp16 transposed feature map.
// ---------------------------------------------------------------------------
__global__ __launch_bounds__(256) void rroi_align_fallback(
    const float* __restrict__ fm,
    const float* __restrict__ boxes,
    float* __restrict__ out)
{
    __shared__ int4   sOff[POS_];
    __shared__ float4 sWgt[POS_];

    const int bn  = blockIdx.x;
    const int b   = bn >> 9;
    const int tid = threadIdx.x;

    if (tid < POS_) {
        const float* bx = boxes + (size_t)bn * 5;
        const float cx = bx[0], cy = bx[1], w = bx[2], h = bx[3], ang = bx[4];
        const float rad = -ang * 0.017453292519943295f;
        const float cr = cosf(rad), sr = sinf(rad);
        const float a00 =  w * (1.0f / W_) * cr;
        const float a01 = -h * (1.0f / H_) * sr;
        const float a02 =  2.0f * cx * (1.0f / W_) - 1.0f;
        const float a10 =  w * (1.0f / W_) * sr;
        const float a11 =  h * (1.0f / H_) * cr;
        const float a12 =  2.0f * cy * (1.0f / H_) - 1.0f;
        const int py = tid / OW_;
        const int px = tid - py * OW_;
        const float xs = (2.0f * (float)px + 1.0f) / (float)OW_ - 1.0f;
        const float ys = (2.0f * (float)py + 1.0f) / (float)OH_ - 1.0f;
        const float gx = a00 * xs + a01 * ys + a02;
        const float gy = a10 * xs + a11 * ys + a12;
        const float ix = ((gx + 1.0f) * (float)W_ - 1.0f) * 0.5f;
        const float iy = ((gy + 1.0f) * (float)H_ - 1.0f) * 0.5f;
        const float x0f = floorf(ix), y0f = floorf(iy);
        const float wx1 = ix - x0f,  wy1 = iy - y0f;
        const float wx0 = 1.0f - wx1, wy0 = 1.0f - wy1;
        const float x1f = x0f + 1.0f, y1f = y0f + 1.0f;
        const float vx0 = (x0f >= 0.0f && x0f <= (float)(W_ - 1)) ? 1.0f : 0.0f;
        const float vx1 = (x1f >= 0.0f && x1f <= (float)(W_ - 1)) ? 1.0f : 0.0f;
        const float vy0 = (y0f >= 0.0f && y0f <= (float)(H_ - 1)) ? 1.0f : 0.0f;
        const float vy1 = (y1f >= 0.0f && y1f <= (float)(H_ - 1)) ? 1.0f : 0.0f;
        const int xi0 = (int)fminf(fmaxf(x0f, 0.0f), (float)(W_ - 1));
        const int xi1 = (int)fminf(fmaxf(x1f, 0.0f), (float)(W_ - 1));
        const int yi0 = (int)fminf(fmaxf(y0f, 0.0f), (float)(H_ - 1));
        const int yi1 = (int)fminf(fmaxf(y1f, 0.0f), (float)(H_ - 1));
        sOff[tid] = make_int4(yi0 * W_ + xi0, yi0 * W_ + xi1,
                              yi1 * W_ + xi0, yi1 * W_ + xi1);
        sWgt[tid] = make_float4(wy0 * wx0 * (vy0 * vx0),
                                wy0 * wx1 * (vy0 * vx1),
                                wy1 * wx0 * (vy1 * vx0),
                                wy1 * wx1 * (vy1 * vx1));
    }
    __syncthreads();

    const float* __restrict__ fb = fm + (size_t)b * C_ * HW_;
    float* __restrict__ ob = out + (size_t)bn * CPB_;

    #pragma unroll 7
    for (int it = 0; it < POS_; ++it) {
        const int flat = it * 256 + tid;
        const int cc   = flat / POS_;
        const int pos  = flat - cc * POS_;
        const int4   o  = sOff[pos];
        const float4 wv = sWgt[pos];
        const float* __restrict__ plane = fb + (size_t)cc * HW_;
        ob[flat] = wv.x * plane[o.x] + wv.y * plane[o.y]
                 + wv.z * plane[o.z] + wv.w * plane[o.w];
    }
}

extern "C" void kernel_launch(void* const* d_in, const int* in_sizes, int n_in,
                              void* d_out, int out_size, void* d_ws, size_t ws_size,
                              hipStream_t stream) {
    const float* fm    = (const float*)d_in[0];
    const float* boxes = (const float*)d_in[1];
    float* out         = (float*)d_out;

    const size_t needed = (size_t)B_ * C_ * HW_ * sizeof(__half);  // 62.3 MB

    if (ws_size >= needed) {
        __half* fmT = (__half*)d_ws;
        transpose_f16_kernel<<<dim3(2 * 950 * 4), dim3(256), 0, stream>>>(fm, fmT);
        gather_f16_kernel<<<dim3(B_ * N_), dim3(256), 0, stream>>>(fmT, boxes, out);
    } else {
        rroi_align_fallback<<<dim3(B_ * N_), dim3(256), 0, stream>>>(fm, boxes, out);
    }
}

// Round 4
// 222.636 us; speedup vs baseline: 2.0796x; 1.0169x over previous
//
#include <hip/hip_runtime.h>
#include <hip/hip_fp16.h>

// Problem constants (from reference setup_inputs)
#define B_   2
#define C_   256
#define H_   200
#define W_   304
#define HW_  60800       // H_*W_
#define N_   512
#define OH_  7
#define OW_  7
#define POS_ 49          // OH_*OW_
#define CPB_ 12544       // C_*POS_  (outputs per box)

#define TP_PITCH 260     // halves per hw-row in LDS: 520B row (8B aligned),
                         // 4*130dw%32==8 -> b64 writes/reads hit 4-beat floor
#define GP_PITCH 264     // gather staging pitch (halves), 8B aligned

// ---------------------------------------------------------------------------
// Pass 1 v3: transpose + fp32->fp16: (B, C, HW) -> (B, HW, C).
// One block = 64 hw x 256 c. 16 outstanding dwordx4 loads/thread, in-register
// 4x4 fp16 transpose, ds_write_b64, ONE barrier, 16B global stores that form
// full contiguous 512B fmT rows.
// ---------------------------------------------------------------------------
__global__ __launch_bounds__(256) void transpose_f16_v3(
    const float* __restrict__ fm,   // (B, C, HW) fp32
    ushort* __restrict__ fmT)       // (B, HW, C) fp16 bits
{
    __shared__ ushort tile[64 * TP_PITCH];   // [hw][c], 33.3 KB

    const int blk = blockIdx.x;        // 0..1899
    const int b   = blk / 950;
    const int hwT = blk - b * 950;
    const int hw0 = hwT * 64;

    const int t = threadIdx.x;

    const float* __restrict__ src = fm + (size_t)b * C_ * HW_ + hw0;

    // ---- load phase: 4 patches of (4c x 4hw) per thread, 16 loads in flight
    float4 r[4][4];
    #pragma unroll
    for (int i = 0; i < 4; ++i) {
        const int p  = i * 256 + t;
        const int cq = p >> 4;          // 0..63  (c = cq*4)
        const int hq = p & 15;          // 0..15  (hw = hq*4)
        #pragma unroll
        for (int j = 0; j < 4; ++j) {
            r[i][j] = *(const float4*)(src + (size_t)(cq * 4 + j) * HW_ + hq * 4);
        }
    }

    // ---- convert + in-register 4x4 transpose -> ds_write_b64
    #pragma unroll
    for (int i = 0; i < 4; ++i) {
        const int p  = i * 256 + t;
        const int cq = p >> 4;
        const int hq = p & 15;
        #pragma unroll
        for (int j2 = 0; j2 < 4; ++j2) {   // hw element within the quad
            ushort4 u;
            u.x = __half_as_ushort(__float2half_rn(((const float*)&r[i][0])[j2]));
            u.y = __half_as_ushort(__float2half_rn(((const float*)&r[i][1])[j2]));
            u.z = __half_as_ushort(__float2half_rn(((const float*)&r[i][2])[j2]));
            u.w = __half_as_ushort(__float2half_rn(((const float*)&r[i][3])[j2]));
            *(ushort4*)&tile[(hq * 4 + j2) * TP_PITCH + cq * 4] = u;
        }
    }
    __syncthreads();

    // ---- store phase: full 512B rows, 16B per lane
    ushort* __restrict__ dst = fmT + ((size_t)b * HW_ + hw0) * C_;
    const int lane32 = t & 31;
    const int rsub   = t >> 5;          // 0..7

    #pragma unroll
    for (int k = 0; k < 8; ++k) {
        const int row = k * 8 + rsub;   // 0..63
        const ushort* sp = &tile[row * TP_PITCH + lane32 * 8];
        const uint2 lo = *(const uint2*)(sp);
        const uint2 hi = *(const uint2*)(sp + 4);
        uint4 v; v.x = lo.x; v.y = lo.y; v.z = hi.x; v.w = hi.y;
        *(uint4*)(dst + (size_t)row * C_ + lane32 * 8) = v;
    }
}

// ---------------------------------------------------------------------------
// Pass 2 v2: gather. One block per box. Lane = 4 channels (8B ushort4 taps,
// 512B fully-used wave segments). fp16 LDS staging, float4 output stores.
// ---------------------------------------------------------------------------
__global__ __launch_bounds__(256) void gather_f16_v2(
    const ushort* __restrict__ fmT,   // (B, HW, C) fp16 bits
    const float* __restrict__ boxes,  // (B, N, 5)
    float* __restrict__ out)          // (B*N, C, 7, 7) fp32
{
    __shared__ int4   sOff[POS_];              // tap offsets (pre-scaled by C_)
    __shared__ float4 sWgt[POS_];              // weights with validity folded
    __shared__ ushort sVal[POS_ * GP_PITCH];   // [pos][c] fp16, 25.9 KB

    const int bn  = blockIdx.x;       // 0 .. B*N-1
    const int b   = bn >> 9;          // N_ = 512
    const int tid = threadIdx.x;

    if (tid < POS_) {
        const float* bx = boxes + (size_t)bn * 5;
        const float cx = bx[0], cy = bx[1], w = bx[2], h = bx[3], ang = bx[4];

        const float rad = -ang * 0.017453292519943295f;   // -pi/180
        const float cr = cosf(rad), sr = sinf(rad);

        const float a00 =  w * (1.0f / W_) * cr;
        const float a01 = -h * (1.0f / H_) * sr;
        const float a02 =  2.0f * cx * (1.0f / W_) - 1.0f;
        const float a10 =  w * (1.0f / W_) * sr;
        const float a11 =  h * (1.0f / H_) * cr;
        const float a12 =  2.0f * cy * (1.0f / H_) - 1.0f;

        const int py = tid / OW_;
        const int px = tid - py * OW_;
        const float xs = (2.0f * (float)px + 1.0f) / (float)OW_ - 1.0f;
        const float ys = (2.0f * (float)py + 1.0f) / (float)OH_ - 1.0f;

        const float gx = a00 * xs + a01 * ys + a02;
        const float gy = a10 * xs + a11 * ys + a12;

        const float ix = ((gx + 1.0f) * (float)W_ - 1.0f) * 0.5f;
        const float iy = ((gy + 1.0f) * (float)H_ - 1.0f) * 0.5f;

        const float x0f = floorf(ix), y0f = floorf(iy);
        const float wx1 = ix - x0f,  wy1 = iy - y0f;
        const float wx0 = 1.0f - wx1, wy0 = 1.0f - wy1;
        const float x1f = x0f + 1.0f, y1f = y0f + 1.0f;

        const float vx0 = (x0f >= 0.0f && x0f <= (float)(W_ - 1)) ? 1.0f : 0.0f;
        const float vx1 = (x1f >= 0.0f && x1f <= (float)(W_ - 1)) ? 1.0f : 0.0f;
        const float vy0 = (y0f >= 0.0f && y0f <= (float)(H_ - 1)) ? 1.0f : 0.0f;
        const float vy1 = (y1f >= 0.0f && y1f <= (float)(H_ - 1)) ? 1.0f : 0.0f;

        const int xi0 = (int)fminf(fmaxf(x0f, 0.0f), (float)(W_ - 1));
        const int xi1 = (int)fminf(fmaxf(x1f, 0.0f), (float)(W_ - 1));
        const int yi0 = (int)fminf(fmaxf(y0f, 0.0f), (float)(H_ - 1));
        const int yi1 = (int)fminf(fmaxf(y1f, 0.0f), (float)(H_ - 1));

        sOff[tid] = make_int4((yi0 * W_ + xi0) * C_, (yi0 * W_ + xi1) * C_,
                              (yi1 * W_ + xi0) * C_, (yi1 * W_ + xi1) * C_);
        sWgt[tid] = make_float4(wy0 * wx0 * (vy0 * vx0),
                                wy0 * wx1 * (vy0 * vx1),
                                wy1 * wx0 * (vy1 * vx0),
                                wy1 * wx1 * (vy1 * vx1));
    }
    __syncthreads();

    const int lane = tid & 63;
    const int pg   = tid >> 6;          // 0..3 (pos phase)
    const int c    = lane * 4;

    const ushort* __restrict__ fb = fmT + (size_t)b * HW_ * C_ + c;

    for (int pos = pg; pos < POS_; pos += 4) {
        const int4   o  = sOff[pos];
        const float4 wv = sWgt[pos];

        const ushort4 q0 = *(const ushort4*)(fb + o.x);
        const ushort4 q1 = *(const ushort4*)(fb + o.y);
        const ushort4 q2 = *(const ushort4*)(fb + o.z);
        const ushort4 q3 = *(const ushort4*)(fb + o.w);

        ushort4 u;
        {
            const float a = wv.x * __half2float(__ushort_as_half(q0.x))
                          + wv.y * __half2float(__ushort_as_half(q1.x))
                          + wv.z * __half2float(__ushort_as_half(q2.x))
                          + wv.w * __half2float(__ushort_as_half(q3.x));
            u.x = __half_as_ushort(__float2half_rn(a));
        }
        {
            const float a = wv.x * __half2float(__ushort_as_half(q0.y))
                          + wv.y * __half2float(__ushort_as_half(q1.y))
                          + wv.z * __half2float(__ushort_as_half(q2.y))
                          + wv.w * __half2float(__ushort_as_half(q3.y));
            u.y = __half_as_ushort(__float2half_rn(a));
        }
        {
            const float a = wv.x * __half2float(__ushort_as_half(q0.z))
                          + wv.y * __half2float(__ushort_as_half(q1.z))
                          + wv.z * __half2float(__ushort_as_half(q2.z))
                          + wv.w * __half2float(__ushort_as_half(q3.z));
            u.z = __half_as_ushort(__float2half_rn(a));
        }
        {
            const float a = wv.x * __half2float(__ushort_as_half(q0.w))
                          + wv.y * __half2float(__ushort_as_half(q1.w))
                          + wv.z * __half2float(__ushort_as_half(q2.w))
                          + wv.w * __half2float(__ushort_as_half(q3.w));
            u.w = __half_as_ushort(__float2half_rn(a));
        }
        *(ushort4*)&sVal[pos * GP_PITCH + c] = u;
    }
    __syncthreads();

    float* __restrict__ ob = out + (size_t)bn * CPB_;

    #pragma unroll
    for (int it = 0; it < 13; ++it) {
        const int flat4 = it * 256 + tid;     // float4 index, < 3136
        if (flat4 < 3136) {
            const int base = flat4 * 4;
            float4 v;
            {
                const int f = base + 0; const int cc = f / POS_; const int pp = f - cc * POS_;
                v.x = __half2float(__ushort_as_half(sVal[pp * GP_PITCH + cc]));
            }
            {
                const int f = base + 1; const int cc = f / POS_; const int pp = f - cc * POS_;
                v.y = __half2float(__ushort_as_half(sVal[pp * GP_PITCH + cc]));
            }
            {
                const int f = base + 2; const int cc = f / POS_; const int pp = f - cc * POS_;
                v.z = __half2float(__ushort_as_half(sVal[pp * GP_PITCH + cc]));
            }
            {
                const int f = base + 3; const int cc = f / POS_; const int pp = f - cc * POS_;
                v.w = __half2float(__ushort_as_half(sVal[pp * GP_PITCH + cc]));
            }
            *(float4*)(ob + base) = v;        // coalesced 16B store
        }
    }
}

// ---------------------------------------------------------------------------
// Fallback (R0 kernel): direct gather from (B,C,H,W) fp32 — used only if the
// workspace is too small for the fp16 transposed feature map.
// ---------------------------------------------------------------------------
__global__ __launch_bounds__(256) void rroi_align_fallback(
    const float* __restrict__ fm,
    const float* __restrict__ boxes,
    float* __restrict__ out)
{
    __shared__ int4   sOff[POS_];
    __shared__ float4 sWgt[POS_];

    const int bn  = blockIdx.x;
    const int b   = bn >> 9;
    const int tid = threadIdx.x;

    if (tid < POS_) {
        const float* bx = boxes + (size_t)bn * 5;
        const float cx = bx[0], cy = bx[1], w = bx[2], h = bx[3], ang = bx[4];
        const float rad = -ang * 0.017453292519943295f;
        const float cr = cosf(rad), sr = sinf(rad);
        const float a00 =  w * (1.0f / W_) * cr;
        const float a01 = -h * (1.0f / H_) * sr;
        const float a02 =  2.0f * cx * (1.0f / W_) - 1.0f;
        const float a10 =  w * (1.0f / W_) * sr;
        const float a11 =  h * (1.0f / H_) * cr;
        const float a12 =  2.0f * cy * (1.0f / H_) - 1.0f;
        const int py = tid / OW_;
        const int px = tid - py * OW_;
        const float xs = (2.0f * (float)px + 1.0f) / (float)OW_ - 1.0f;
        const float ys = (2.0f * (float)py + 1.0f) / (float)OH_ - 1.0f;
        const float gx = a00 * xs + a01 * ys + a02;
        const float gy = a10 * xs + a11 * ys + a12;
        const float ix = ((gx + 1.0f) * (float)W_ - 1.0f) * 0.5f;
        const float iy = ((gy + 1.0f) * (float)H_ - 1.0f) * 0.5f;
        const float x0f = floorf(ix), y0f = floorf(iy);
        const float wx1 = ix - x0f,  wy1 = iy - y0f;
        const float wx0 = 1.0f - wx1, wy0 = 1.0f - wy1;
        const float x1f = x0f + 1.0f, y1f = y0f + 1.0f;
        const float vx0 = (x0f >= 0.0f && x0f <= (float)(W_ - 1)) ? 1.0f : 0.0f;
        const float vx1 = (x1f >= 0.0f && x1f <= (float)(W_ - 1)) ? 1.0f : 0.0f;
        const float vy0 = (y0f >= 0.0f && y0f <= (float)(H_ - 1)) ? 1.0f : 0.0f;
        const float vy1 = (y1f >= 0.0f && y1f <= (float)(H_ - 1)) ? 1.0f : 0.0f;
        const int xi0 = (int)fminf(fmaxf(x0f, 0.0f), (float)(W_ - 1));
        const int xi1 = (int)fminf(fmaxf(x1f, 0.0f), (float)(W_ - 1));
        const int yi0 = (int)fminf(fmaxf(y0f, 0.0f), (float)(H_ - 1));
        const int yi1 = (int)fminf(fmaxf(y1f, 0.0f), (float)(H_ - 1));
        sOff[tid] = make_int4(yi0 * W_ + xi0, yi0 * W_ + xi1,
                              yi1 * W_ + xi0, yi1 * W_ + xi1);
        sWgt[tid] = make_float4(wy0 * wx0 * (vy0 * vx0),
                                wy0 * wx1 * (vy0 * vx1),
                                wy1 * wx0 * (vy1 * vx0),
                                wy1 * wx1 * (vy1 * vx1));
    }
    __syncthreads();

    const float* __restrict__ fb = fm + (size_t)b * C_ * HW_;
    float* __restrict__ ob = out + (size_t)bn * CPB_;

    #pragma unroll 7
    for (int it = 0; it < POS_; ++it) {
        const int flat = it * 256 + tid;
        const int cc   = flat / POS_;
        const int pos  = flat - cc * POS_;
        const int4   o  = sOff[pos];
        const float4 wv = sWgt[pos];
        const float* __restrict__ plane = fb + (size_t)cc * HW_;
        ob[flat] = wv.x * plane[o.x] + wv.y * plane[o.y]
                 + wv.z * plane[o.z] + wv.w * plane[o.w];
    }
}

extern "C" void kernel_launch(void* const* d_in, const int* in_sizes, int n_in,
                              void* d_out, int out_size, void* d_ws, size_t ws_size,
                              hipStream_t stream) {
    const float* fm    = (const float*)d_in[0];
    const float* boxes = (const float*)d_in[1];
    float* out         = (float*)d_out;

    const size_t needed = (size_t)B_ * C_ * HW_ * sizeof(ushort);  // 62.3 MB

    if (ws_size >= needed) {
        ushort* fmT = (ushort*)d_ws;
        transpose_f16_v3<<<dim3(2 * 950), dim3(256), 0, stream>>>(fm, fmT);
        gather_f16_v2<<<dim3(B_ * N_), dim3(256), 0, stream>>>(fmT, boxes, out);
    } else {
        rroi_align_fallback<<<dim3(B_ * N_), dim3(256), 0, stream>>>(fm, boxes, out);
    }
}

// Round 5
// 222.347 us; speedup vs baseline: 2.0823x; 1.0013x over previous
//
#include <hip/hip_runtime.h>
#include <hip/hip_fp16.h>

// Problem constants (from reference setup_inputs)
#define B_   2
#define C_   256
#define H_   200
#define W_   304
#define HW_  60800       // H_*W_
#define N_   512
#define OH_  7
#define OW_  7
#define POS_ 49          // OH_*OW_
#define CPB_ 12544       // C_*POS_  (outputs per box)

#define GP_PITCH 264     // gather staging pitch (halves), 8B aligned

// ---------------------------------------------------------------------------
// Pass 1 v5: transpose + fp32->fp16: (B, C, HW) -> (B, HW, C).
// Tile = 128 hw x 128 c (c-half per block) so each channel-row read burst is
// 512 B (2x R4) to test the DRAM-page-efficiency theory. Un-padded 32 KB LDS
// tile with XOR quad swizzle: q' = q ^ 2*((row>>2)&7) — even f keeps uint4
// reads contiguous, spreads ds_write_b64 banks to ~4-way.
// ---------------------------------------------------------------------------
__global__ __launch_bounds__(256) void transpose_f16_v5(
    const float* __restrict__ fm,   // (B, C, HW) fp32
    ushort* __restrict__ fmT)       // (B, HW, C) fp16 bits
{
    __shared__ ushort tile[128 * 128];   // [hw][c'], 32 KB, swizzled quads

    const int blk = blockIdx.x;          // 0..1899
    const int b   = blk / 950;
    const int r0  = blk - b * 950;
    const int ch  = r0 / 475;            // c-half 0/1
    const int hwT = r0 - ch * 475;       // 0..474
    const int hw0 = hwT * 128;
    const int c0  = ch * 128;

    const int t = threadIdx.x;

    const float* __restrict__ src = fm + ((size_t)(b * C_ + c0)) * HW_ + hw0;

    // ---- load phase: 4 patches of (4c x 4hw)/thread; wave inst = 2x512B rows
    float4 rg[4][4];
    #pragma unroll
    for (int i = 0; i < 4; ++i) {
        const int p  = i * 256 + t;
        const int hq = p & 31;           // hw quad 0..31
        const int cq = p >> 5;           // c  quad 0..31
        #pragma unroll
        for (int j = 0; j < 4; ++j)
            rg[i][j] = *(const float4*)(src + (size_t)(cq * 4 + j) * HW_ + hq * 4);
    }

    // ---- convert + 4x4 register transpose -> ds_write_b64 (swizzled)
    #pragma unroll
    for (int i = 0; i < 4; ++i) {
        const int p  = i * 256 + t;
        const int hq = p & 31;
        const int cq = p >> 5;
        const int qs = cq ^ ((hq & 7) << 1);   // f(row)=2*((row>>2)&7), row>>2==hq
        #pragma unroll
        for (int j2 = 0; j2 < 4; ++j2) {       // hw element within the quad
            const int row = hq * 4 + j2;
            ushort4 u;
            u.x = __half_as_ushort(__float2half_rn(((const float*)&rg[i][0])[j2]));
            u.y = __half_as_ushort(__float2half_rn(((const float*)&rg[i][1])[j2]));
            u.z = __half_as_ushort(__float2half_rn(((const float*)&rg[i][2])[j2]));
            u.w = __half_as_ushort(__float2half_rn(((const float*)&rg[i][3])[j2]));
            *(ushort4*)&tile[row * 128 + qs * 4] = u;
        }
    }
    __syncthreads();

    // ---- store phase: 16B/lane; wave inst = 4 rows x 256 B
    ushort* __restrict__ dst = fmT + ((size_t)(b * HW_ + hw0)) * C_ + c0;

    #pragma unroll
    for (int s = 0; s < 8; ++s) {
        const int g   = s * 256 + t;     // 0..2047
        const int row = g >> 4;          // 0..127
        const int m   = g & 15;          // ushort8 block within the 128-c half
        const int msw = m ^ ((row >> 2) & 7);   // un-swizzle (2m ^ 2g = 2(m^g))
        const uint4 v = *(const uint4*)&tile[row * 128 + msw * 8];
        *(uint4*)(dst + (size_t)row * C_ + m * 8) = v;
    }
}

// ---------------------------------------------------------------------------
// Pass 2 (UNCHANGED from R4): gather. One block per box. Lane = 4 channels
// (8B ushort4 taps, 512B fully-used wave segments). fp16 LDS staging,
// float4 output stores.
// ---------------------------------------------------------------------------
__global__ __launch_bounds__(256) void gather_f16_v2(
    const ushort* __restrict__ fmT,   // (B, HW, C) fp16 bits
    const float* __restrict__ boxes,  // (B, N, 5)
    float* __restrict__ out)          // (B*N, C, 7, 7) fp32
{
    __shared__ int4   sOff[POS_];              // tap offsets (pre-scaled by C_)
    __shared__ float4 sWgt[POS_];              // weights with validity folded
    __shared__ ushort sVal[POS_ * GP_PITCH];   // [pos][c] fp16, 25.9 KB

    const int bn  = blockIdx.x;       // 0 .. B*N-1
    const int b   = bn >> 9;          // N_ = 512
    const int tid = threadIdx.x;

    if (tid < POS_) {
        const float* bx = boxes + (size_t)bn * 5;
        const float cx = bx[0], cy = bx[1], w = bx[2], h = bx[3], ang = bx[4];

        const float rad = -ang * 0.017453292519943295f;   // -pi/180
        const float cr = cosf(rad), sr = sinf(rad);

        const float a00 =  w * (1.0f / W_) * cr;
        const float a01 = -h * (1.0f / H_) * sr;
        const float a02 =  2.0f * cx * (1.0f / W_) - 1.0f;
        const float a10 =  w * (1.0f / W_) * sr;
        const float a11 =  h * (1.0f / H_) * cr;
        const float a12 =  2.0f * cy * (1.0f / H_) - 1.0f;

        const int py = tid / OW_;
        const int px = tid - py * OW_;
        const float xs = (2.0f * (float)px + 1.0f) / (float)OW_ - 1.0f;
        const float ys = (2.0f * (float)py + 1.0f) / (float)OH_ - 1.0f;

        const float gx = a00 * xs + a01 * ys + a02;
        const float gy = a10 * xs + a11 * ys + a12;

        const float ix = ((gx + 1.0f) * (float)W_ - 1.0f) * 0.5f;
        const float iy = ((gy + 1.0f) * (float)H_ - 1.0f) * 0.5f;

        const float x0f = floorf(ix), y0f = floorf(iy);
        const float wx1 = ix - x0f,  wy1 = iy - y0f;
        const float wx0 = 1.0f - wx1, wy0 = 1.0f - wy1;
        const float x1f = x0f + 1.0f, y1f = y0f + 1.0f;

        const float vx0 = (x0f >= 0.0f && x0f <= (float)(W_ - 1)) ? 1.0f : 0.0f;
        const float vx1 = (x1f >= 0.0f && x1f <= (float)(W_ - 1)) ? 1.0f : 0.0f;
        const float vy0 = (y0f >= 0.0f && y0f <= (float)(H_ - 1)) ? 1.0f : 0.0f;
        const float vy1 = (y1f >= 0.0f && y1f <= (float)(H_ - 1)) ? 1.0f : 0.0f;

        const int xi0 = (int)fminf(fmaxf(x0f, 0.0f), (float)(W_ - 1));
        const int xi1 = (int)fminf(fmaxf(x1f, 0.0f), (float)(W_ - 1));
        const int yi0 = (int)fminf(fmaxf(y0f, 0.0f), (float)(H_ - 1));
        const int yi1 = (int)fminf(fmaxf(y1f, 0.0f), (float)(H_ - 1));

        sOff[tid] = make_int4((yi0 * W_ + xi0) * C_, (yi0 * W_ + xi1) * C_,
                              (yi1 * W_ + xi0) * C_, (yi1 * W_ + xi1) * C_);
        sWgt[tid] = make_float4(wy0 * wx0 * (vy0 * vx0),
                                wy0 * wx1 * (vy0 * vx1),
                                wy1 * wx0 * (vy1 * vx0),
                                wy1 * wx1 * (vy1 * vx1));
    }
    __syncthreads();

    const int lane = tid & 63;
    const int pg   = tid >> 6;          // 0..3 (pos phase)
    const int c    = lane * 4;

    const ushort* __restrict__ fb = fmT + (size_t)b * HW_ * C_ + c;

    for (int pos = pg; pos < POS_; pos += 4) {
        const int4   o  = sOff[pos];
        const float4 wv = sWgt[pos];

        const ushort4 q0 = *(const ushort4*)(fb + o.x);
        const ushort4 q1 = *(const ushort4*)(fb + o.y);
        const ushort4 q2 = *(const ushort4*)(fb + o.z);
        const ushort4 q3 = *(const ushort4*)(fb + o.w);

        ushort4 u;
        {
            const float a = wv.x * __half2float(__ushort_as_half(q0.x))
                          + wv.y * __half2float(__ushort_as_half(q1.x))
                          + wv.z * __half2float(__ushort_as_half(q2.x))
                          + wv.w * __half2float(__ushort_as_half(q3.x));
            u.x = __half_as_ushort(__float2half_rn(a));
        }
        {
            const float a = wv.x * __half2float(__ushort_as_half(q0.y))
                          + wv.y * __half2float(__ushort_as_half(q1.y))
                          + wv.z * __half2float(__ushort_as_half(q2.y))
                          + wv.w * __half2float(__ushort_as_half(q3.y));
            u.y = __half_as_ushort(__float2half_rn(a));
        }
        {
            const float a = wv.x * __half2float(__ushort_as_half(q0.z))
                          + wv.y * __half2float(__ushort_as_half(q1.z))
                          + wv.z * __half2float(__ushort_as_half(q2.z))
                          + wv.w * __half2float(__ushort_as_half(q3.z));
            u.z = __half_as_ushort(__float2half_rn(a));
        }
        {
            const float a = wv.x * __half2float(__ushort_as_half(q0.w))
                          + wv.y * __half2float(__ushort_as_half(q1.w))
                          + wv.z * __half2float(__ushort_as_half(q2.w))
                          + wv.w * __half2float(__ushort_as_half(q3.w));
            u.w = __half_as_ushort(__float2half_rn(a));
        }
        *(ushort4*)&sVal[pos * GP_PITCH + c] = u;
    }
    __syncthreads();

    float* __restrict__ ob = out + (size_t)bn * CPB_;

    #pragma unroll
    for (int it = 0; it < 13; ++it) {
        const int flat4 = it * 256 + tid;     // float4 index, < 3136
        if (flat4 < 3136) {
            const int base = flat4 * 4;
            float4 v;
            {
                const int f = base + 0; const int cc = f / POS_; const int pp = f - cc * POS_;
                v.x = __half2float(__ushort_as_half(sVal[pp * GP_PITCH + cc]));
            }
            {
                const int f = base + 1; const int cc = f / POS_; const int pp = f - cc * POS_;
                v.y = __half2float(__ushort_as_half(sVal[pp * GP_PITCH + cc]));
            }
            {
                const int f = base + 2; const int cc = f / POS_; const int pp = f - cc * POS_;
                v.z = __half2float(__ushort_as_half(sVal[pp * GP_PITCH + cc]));
            }
            {
                const int f = base + 3; const int cc = f / POS_; const int pp = f - cc * POS_;
                v.w = __half2float(__ushort_as_half(sVal[pp * GP_PITCH + cc]));
            }
            *(float4*)(ob + base) = v;        // coalesced 16B store
        }
    }
}

// ---------------------------------------------------------------------------
// Fallback (R0 kernel): direct gather from (B,C,H,W) fp32 — used only if the
// workspace is too small for the fp16 transposed feature map.
// ---------------------------------------------------------------------------
__global__ __launch_bounds__(256) void rroi_align_fallback(
    const float* __restrict__ fm,
    const float* __restrict__ boxes,
    float* __restrict__ out)
{
    __shared__ int4   sOff[POS_];
    __shared__ float4 sWgt[POS_];

    const int bn  = blockIdx.x;
    const int b   = bn >> 9;
    const int tid = threadIdx.x;

    if (tid < POS_) {
        const float* bx = boxes + (size_t)bn * 5;
        const float cx = bx[0], cy = bx[1], w = bx[2], h = bx[3], ang = bx[4];
        const float rad = -ang * 0.017453292519943295f;
        const float cr = cosf(rad), sr = sinf(rad);
        const float a00 =  w * (1.0f / W_) * cr;
        const float a01 = -h * (1.0f / H_) * sr;
        const float a02 =  2.0f * cx * (1.0f / W_) - 1.0f;
        const float a10 =  w * (1.0f / W_) * sr;
        const float a11 =  h * (1.0f / H_) * cr;
        const float a12 =  2.0f * cy * (1.0f / H_) - 1.0f;
        const int py = tid / OW_;
        const int px = tid - py * OW_;
        const float xs = (2.0f * (float)px + 1.0f) / (float)OW_ - 1.0f;
        const float ys = (2.0f * (float)py + 1.0f) / (float)OH_ - 1.0f;
        const float gx = a00 * xs + a01 * ys + a02;
        const float gy = a10 * xs + a11 * ys + a12;
        const float ix = ((gx + 1.0f) * (float)W_ - 1.0f) * 0.5f;
        const float iy = ((gy + 1.0f) * (float)H_ - 1.0f) * 0.5f;
        const float x0f = floorf(ix), y0f = floorf(iy);
        const float wx1 = ix - x0f,  wy1 = iy - y0f;
        const float wx0 = 1.0f - wx1, wy0 = 1.0f - wy1;
        const float x1f = x0f + 1.0f, y1f = y0f + 1.0f;
        const float vx0 = (x0f >= 0.0f && x0f <= (float)(W_ - 1)) ? 1.0f : 0.0f;
        const float vx1 = (x1f >= 0.0f && x1f <= (float)(W_ - 1)) ? 1.0f : 0.0f;
        const float vy0 = (y0f >= 0.0f && y0f <= (float)(H_ - 1)) ? 1.0f : 0.0f;
        const float vy1 = (y1f >= 0.0f && y1f <= (float)(H_ - 1)) ? 1.0f : 0.0f;
        const int xi0 = (int)fminf(fmaxf(x0f, 0.0f), (float)(W_ - 1));
        const int xi1 = (int)fminf(fmaxf(x1f, 0.0f), (float)(W_ - 1));
        const int yi0 = (int)fminf(fmaxf(y0f, 0.0f), (float)(H_ - 1));
        const int yi1 = (int)fminf(fmaxf(y1f, 0.0f), (float)(H_ - 1));
        sOff[tid] = make_int4(yi0 * W_ + xi0, yi0 * W_ + xi1,
                              yi1 * W_ + xi0, yi1 * W_ + xi1);
        sWgt[tid] = make_float4(wy0 * wx0 * (vy0 * vx0),
                                wy0 * wx1 * (vy0 * vx1),
                                wy1 * wx0 * (vy1 * vx0),
                                wy1 * wx1 * (vy1 * vx1));
    }
    __syncthreads();

    const float* __restrict__ fb = fm + (size_t)b * C_ * HW_;
    float* __restrict__ ob = out + (size_t)bn * CPB_;

    #pragma unroll 7
    for (int it = 0; it < POS_; ++it) {
        const int flat = it * 256 + tid;
        const int cc   = flat / POS_;
        const int pos  = flat - cc * POS_;
        const int4   o  = sOff[pos];
        const float4 wv = sWgt[pos];
        const float* __restrict__ plane = fb + (size_t)cc * HW_;
        ob[flat] = wv.x * plane[o.x] + wv.y * plane[o.y]
                 + wv.z * plane[o.z] + wv.w * plane[o.w];
    }
}

extern "C" void kernel_launch(void* const* d_in, const int* in_sizes, int n_in,
                              void* d_out, int out_size, void* d_ws, size_t ws_size,
                              hipStream_t stream) {
    const float* fm    = (const float*)d_in[0];
    const float* boxes = (const float*)d_in[1];
    float* out         = (float*)d_out;

    const size_t needed = (size_t)B_ * C_ * HW_ * sizeof(ushort);  // 62.3 MB

    if (ws_size >= needed) {
        ushort* fmT = (ushort*)d_ws;
        transpose_f16_v5<<<dim3(1900), dim3(256), 0, stream>>>(fm, fmT);
        gather_f16_v2<<<dim3(B_ * N_), dim3(256), 0, stream>>>(fmT, boxes, out);
    } else {
        rroi_align_fallback<<<dim3(B_ * N_), dim3(256), 0, stream>>>(fm, boxes, out);
    }
}